// Round 1
// baseline (53.949 us; speedup 1.0000x reference)
//
#include <hip/hip_runtime.h>

#define BLOCK 256
#define TILE 64
#define PR 40          // patch rows/cols in xp-space (32 + 8 halo)
#define PITCH 44       // mult of 4 -> 16B-aligned rows; 44%32=12 spreads banks
#define HW 256
#define OWID 512

typedef float f32x4 __attribute__((ext_vector_type(4)));

__global__ __launch_bounds__(BLOCK, 6) void up2d_kernel(
    const float* __restrict__ x,
    const float* __restrict__ f,
    float* __restrict__ out)
{
    __shared__ __align__(16) float P[PR][PITCH];    // P[c][r] transposed patch
    __shared__ __align__(16) float T[TILE][PITCH];  // T[orow][c] vertical result

    const int tid = threadIdx.x;
    const int tile = blockIdx.x;   // 0..63
    const int bc   = blockIdx.y;   // 0..127
    const int ty = (tile >> 3) * TILE;
    const int tx = (tile & 7) * TILE;
    const int ry0 = (ty >> 1) - 1;
    const int rx0 = (tx >> 1) - 1;

    // Effective 17-tap filter: g[d], d = |offset|
    float g[9];
    g[0] = 4.0f * f[7];
#pragma unroll
    for (int k = 1; k <= 7; ++k) g[k] = 2.0f * (f[7 + k] + f[6 + k]);
    g[8] = 2.0f * f[14];

    float wE[9], wO[8];
#pragma unroll
    for (int q = 0; q < 9; ++q) { int d = 8 - 2 * q; wE[q] = g[d < 0 ? -d : d]; }
#pragma unroll
    for (int q = 0; q < 8; ++q) { int d = 7 - 2 * q; wO[q] = g[d < 0 ? -d : d]; }
    const float g7 = g[7], g8 = g[8];

    // ---- Stage 1: load 40x40 patch (transposed, zero-guarded) ----
    const float* xc = x + (size_t)bc * (HW * HW);
#pragma unroll
    for (int it = 0; it < 7; ++it) {
        int w = it * BLOCK + tid;
        if (w < PR * PR) {
            int r = w / PR;
            int c = w - r * PR;
            int gr = ry0 + r, gc = rx0 + c;
            int sr = gr - 3; sr = sr < 0 ? -sr : sr; sr = sr >= HW ? 2 * HW - 2 - sr : sr;
            int sc = gc - 3; sc = sc < 0 ? -sc : sc; sc = sc >= HW ? 2 * HW - 2 - sc : sc;
            float v = xc[sr * HW + sc];
            if ((unsigned)gr >= 262u || (unsigned)gc >= 262u) v = 0.0f;  // guard slots
            P[c][r] = v;
        }
    }
    __syncthreads();

    // ---- Stage 2: vertical filter; 4 row-pairs (8 out rows) per item ----
    // 320 items = 8 kgroups x 40 cols; reads = 3x ds_read_b128 (sliding window)
#pragma unroll
    for (int it = 0; it < 2; ++it) {
        int w = it * BLOCK + tid;
        if (w < 8 * PR) {
            int kg = w / PR;            // 0..7  -> pairs 4kg..4kg+3
            int c  = w - kg * PR;       // 0..39
            f32x4 a0 = *reinterpret_cast<const f32x4*>(&P[c][4 * kg]);
            f32x4 a1 = *reinterpret_cast<const f32x4*>(&P[c][4 * kg + 4]);
            f32x4 a2 = *reinterpret_cast<const f32x4*>(&P[c][4 * kg + 8]);
            float v[12] = {a0[0],a0[1],a0[2],a0[3],
                           a1[0],a1[1],a1[2],a1[3],
                           a2[0],a2[1],a2[2],a2[3]};
#pragma unroll
            for (int t = 0; t < 4; ++t) {
                float aE = 0.0f, aO = 0.0f;
#pragma unroll
                for (int q = 0; q < 9; ++q) aE = fmaf(wE[q], v[t + q], aE);
#pragma unroll
                for (int q = 0; q < 8; ++q) aO = fmaf(wO[q], v[t + 1 + q], aO);
                int k = 4 * kg + t;
                if (ty == 0 && k == 0)    { aE += g7 * v[1]; aO += g8 * v[1]; }
                if (ty == 448 && k == 31) { aO += g8 * v[10]; }
                T[2 * k][c]     = aE;
                T[2 * k + 1][c] = aO;
            }
        }
    }
    __syncthreads();

    // ---- Stage 3: horizontal filter; 8 out cols per item ----
    // 512 items = 64 rows x 8 col-groups; reads = 3x ds_read_b128
    const float inv_s = 0.25231325f;   // 1/sqrt(5*pi)
    float* oc = out + (size_t)bc * ((size_t)OWID * OWID);
#pragma unroll
    for (int it = 0; it < 2; ++it) {
        int w = it * BLOCK + tid;
        int orow = w >> 3;             // 0..63
        int j = w & 7;                 // cols 8j..8j+7
        f32x4 a0 = *reinterpret_cast<const f32x4*>(&T[orow][4 * j]);
        f32x4 a1 = *reinterpret_cast<const f32x4*>(&T[orow][4 * j + 4]);
        f32x4 a2 = *reinterpret_cast<const f32x4*>(&T[orow][4 * j + 8]);
        float v[12] = {a0[0],a0[1],a0[2],a0[3],
                       a1[0],a1[1],a1[2],a1[3],
                       a2[0],a2[1],a2[2],a2[3]};
        float r[8];
#pragma unroll
        for (int t = 0; t < 4; ++t) {
            float e = 0.0f, o = 0.0f;
#pragma unroll
            for (int q = 0; q < 9; ++q) e = fmaf(wE[q], v[t + q], e);
#pragma unroll
            for (int q = 0; q < 8; ++q) o = fmaf(wO[q], v[t + 1 + q], o);
            r[2 * t]     = e;
            r[2 * t + 1] = o;
        }
        if (tx == 0 && j == 0)   { r[0] += g7 * v[1]; r[1] += g8 * v[1]; }
        if (tx == 448 && j == 7) { r[7] += g8 * v[10]; }
        f32x4 o0 = {r[0] * inv_s, r[1] * inv_s, r[2] * inv_s, r[3] * inv_s};
        f32x4 o1 = {r[4] * inv_s, r[5] * inv_s, r[6] * inv_s, r[7] * inv_s};
        float* dst = &oc[(size_t)(ty + orow) * OWID + tx + 8 * j];
        __builtin_nontemporal_store(o0, reinterpret_cast<f32x4*>(dst));
        __builtin_nontemporal_store(o1, reinterpret_cast<f32x4*>(dst) + 1);
    }
}

extern "C" void kernel_launch(void* const* d_in, const int* in_sizes, int n_in,
                              void* d_out, int out_size, void* d_ws, size_t ws_size,
                              hipStream_t stream) {
    const float* x = (const float*)d_in[0];
    const float* f = (const float*)d_in[1];
    float* out = (float*)d_out;
    dim3 grid(64, 128);
    up2d_kernel<<<grid, BLOCK, 0, stream>>>(x, f, out);
}

// Round 2
// 48.687 us; speedup vs baseline: 1.1081x; 1.1081x over previous
//
#include <hip/hip_runtime.h>

#define BLOCK 256
#define TILE 64
#define PR 40          // patch rows/cols in xp-space (32 + 8 halo)
#define PITCH 44       // mult of 4 -> 16B-aligned rows; 44%32=12 spreads banks
#define HW 256
#define OWID 512

typedef float f32x4 __attribute__((ext_vector_type(4)));

__global__ __launch_bounds__(BLOCK) void up2d_kernel(
    const float* __restrict__ x,
    const float* __restrict__ f,
    float* __restrict__ out)
{
    __shared__ __align__(16) float P[PR][PITCH];    // P[c][r] transposed patch
    __shared__ __align__(16) float T[TILE][PITCH];  // T[orow][c] vertical result

    const int tid = threadIdx.x;
    const int tile = blockIdx.x;   // 0..63
    const int bc   = blockIdx.y;   // 0..127
    const int ty = (tile >> 3) * TILE;
    const int tx = (tile & 7) * TILE;
    const int ry0 = (ty >> 1) - 1;
    const int rx0 = (tx >> 1) - 1;

    // Effective 17-tap filter: g[d], d = |offset|
    float g[9];
    g[0] = 4.0f * f[7];
#pragma unroll
    for (int k = 1; k <= 7; ++k) g[k] = 2.0f * (f[7 + k] + f[6 + k]);
    g[8] = 2.0f * f[14];

    float wE[9], wO[8];
#pragma unroll
    for (int q = 0; q < 9; ++q) { int d = 8 - 2 * q; wE[q] = g[d < 0 ? -d : d]; }
#pragma unroll
    for (int q = 0; q < 8; ++q) { int d = 7 - 2 * q; wO[q] = g[d < 0 ? -d : d]; }
    const float g7 = g[7], g8 = g[8];

    // ---- Stage 1: load 40x40 patch (transposed, zero-guarded) ----
    const float* xc = x + (size_t)bc * (HW * HW);
#pragma unroll
    for (int it = 0; it < 7; ++it) {
        int w = it * BLOCK + tid;
        if (w < PR * PR) {
            int r = w / PR;
            int c = w - r * PR;
            int gr = ry0 + r, gc = rx0 + c;
            int sr = gr - 3; sr = sr < 0 ? -sr : sr; sr = sr >= HW ? 2 * HW - 2 - sr : sr;
            int sc = gc - 3; sc = sc < 0 ? -sc : sc; sc = sc >= HW ? 2 * HW - 2 - sc : sc;
            float v = xc[sr * HW + sc];
            if ((unsigned)gr >= 262u || (unsigned)gc >= 262u) v = 0.0f;  // guard slots
            P[c][r] = v;
        }
    }
    __syncthreads();

    // ---- Stage 2: vertical filter; 4 row-pairs (8 out rows) per item ----
    // 320 items = 8 kgroups x 40 cols; reads = 3x ds_read_b128 (sliding window)
#pragma unroll
    for (int it = 0; it < 2; ++it) {
        int w = it * BLOCK + tid;
        if (w < 8 * PR) {
            int kg = w / PR;            // 0..7  -> pairs 4kg..4kg+3
            int c  = w - kg * PR;       // 0..39
            f32x4 a0 = *reinterpret_cast<const f32x4*>(&P[c][4 * kg]);
            f32x4 a1 = *reinterpret_cast<const f32x4*>(&P[c][4 * kg + 4]);
            f32x4 a2 = *reinterpret_cast<const f32x4*>(&P[c][4 * kg + 8]);
            float v[12] = {a0[0],a0[1],a0[2],a0[3],
                           a1[0],a1[1],a1[2],a1[3],
                           a2[0],a2[1],a2[2],a2[3]};
#pragma unroll
            for (int t = 0; t < 4; ++t) {
                float aE = 0.0f, aO = 0.0f;
#pragma unroll
                for (int q = 0; q < 9; ++q) aE = fmaf(wE[q], v[t + q], aE);
#pragma unroll
                for (int q = 0; q < 8; ++q) aO = fmaf(wO[q], v[t + 1 + q], aO);
                int k = 4 * kg + t;
                if (ty == 0 && k == 0)    { aE += g7 * v[1]; aO += g8 * v[1]; }
                if (ty == 448 && k == 31) { aO += g8 * v[10]; }
                T[2 * k][c]     = aE;
                T[2 * k + 1][c] = aO;
            }
        }
    }
    __syncthreads();

    // ---- Stage 3: horizontal filter; 8 out cols per item ----
    // 512 items = 64 rows x 8 col-groups; reads = 3x ds_read_b128
    const float inv_s = 0.25231325f;   // 1/sqrt(5*pi)
    float* oc = out + (size_t)bc * ((size_t)OWID * OWID);
#pragma unroll
    for (int it = 0; it < 2; ++it) {
        int w = it * BLOCK + tid;
        int orow = w >> 3;             // 0..63
        int j = w & 7;                 // cols 8j..8j+7
        f32x4 a0 = *reinterpret_cast<const f32x4*>(&T[orow][4 * j]);
        f32x4 a1 = *reinterpret_cast<const f32x4*>(&T[orow][4 * j + 4]);
        f32x4 a2 = *reinterpret_cast<const f32x4*>(&T[orow][4 * j + 8]);
        float v[12] = {a0[0],a0[1],a0[2],a0[3],
                       a1[0],a1[1],a1[2],a1[3],
                       a2[0],a2[1],a2[2],a2[3]};
        float r[8];
#pragma unroll
        for (int t = 0; t < 4; ++t) {
            float e = 0.0f, o = 0.0f;
#pragma unroll
            for (int q = 0; q < 9; ++q) e = fmaf(wE[q], v[t + q], e);
#pragma unroll
            for (int q = 0; q < 8; ++q) o = fmaf(wO[q], v[t + 1 + q], o);
            r[2 * t]     = e;
            r[2 * t + 1] = o;
        }
        if (tx == 0 && j == 0)   { r[0] += g7 * v[1]; r[1] += g8 * v[1]; }
        if (tx == 448 && j == 7) { r[7] += g8 * v[10]; }
        f32x4 o0 = {r[0] * inv_s, r[1] * inv_s, r[2] * inv_s, r[3] * inv_s};
        f32x4 o1 = {r[4] * inv_s, r[5] * inv_s, r[6] * inv_s, r[7] * inv_s};
        float* dst = &oc[(size_t)(ty + orow) * OWID + tx + 8 * j];
        *reinterpret_cast<f32x4*>(dst) = o0;
        *(reinterpret_cast<f32x4*>(dst) + 1) = o1;
    }
}

extern "C" void kernel_launch(void* const* d_in, const int* in_sizes, int n_in,
                              void* d_out, int out_size, void* d_ws, size_t ws_size,
                              hipStream_t stream) {
    const float* x = (const float*)d_in[0];
    const float* f = (const float*)d_in[1];
    float* out = (float*)d_out;
    dim3 grid(64, 128);
    up2d_kernel<<<grid, BLOCK, 0, stream>>>(x, f, out);
}

// Round 3
// 34.803 us; speedup vs baseline: 1.5501x; 1.3989x over previous
//
#include <hip/hip_runtime.h>

#define BLOCK 256
#define TILE 64
#define PR 40          // TILE/2 + 8 halo (xp-space)
#define HW 256
#define OWID 512

__global__ __launch_bounds__(BLOCK) void up2d_kernel(
    const float* __restrict__ x,
    const float* __restrict__ f,
    float* __restrict__ out)
{
    __shared__ float P[PR][PR + 1];   // P[c][r] = xp[ry0+r][rx0+c], zero-guarded
    __shared__ float T[TILE][42];     // T[orow][c], pitch 42 keeps 8B align

    const int tid = threadIdx.x;

    // XCD-aware remap: 8192 blocks, 8 XCDs. HW assigns XCD = L % 8 (round-robin
    // on dispatch id). Give XCD k the contiguous orig-range [1024k, 1024(k+1)):
    // 16 whole images, tiles of each image temporally clustered on ONE XCD ->
    // each 256 KB image fetched from HBM once, halo re-reads are L2 hits.
    const int L = blockIdx.x;                       // 0..8191
    const int orig = ((L & 7) << 10) | (L >> 3);    // bijective
    const int bc   = orig >> 6;    // 0..127  (image = batch*channel)
    const int tile = orig & 63;    // 0..63   (8x8 tiles of 64x64)

    const int ty = (tile >> 3) * TILE;
    const int tx = (tile & 7) * TILE;
    const int ry0 = (ty >> 1) - 1;
    const int rx0 = (tx >> 1) - 1;

    // Effective 17-tap filter: g[d], d = |offset|
    float g[9];
    g[0] = 4.0f * f[7];
#pragma unroll
    for (int k = 1; k <= 7; ++k) g[k] = 2.0f * (f[7 + k] + f[6 + k]);
    g[8] = 2.0f * f[14];

    float wE[9], wO[8];
#pragma unroll
    for (int q = 0; q < 9; ++q) { int d = 8 - 2 * q; wE[q] = g[d < 0 ? -d : d]; }
#pragma unroll
    for (int q = 0; q < 8; ++q) { int d = 7 - 2 * q; wO[q] = g[d < 0 ? -d : d]; }
    const float g7 = g[7], g8 = g[8];

    // ---- Stage 1: load 40x40 patch (transposed, zero-guarded) ----
    const float* xc = x + (size_t)bc * (HW * HW);
#pragma unroll
    for (int it = 0; it < 7; ++it) {
        int w = it * BLOCK + tid;
        if (w < PR * PR) {
            int r = w / PR;
            int c = w - r * PR;
            int gr = ry0 + r, gc = rx0 + c;
            int sr = gr - 3; sr = sr < 0 ? -sr : sr; sr = sr >= HW ? 2 * HW - 2 - sr : sr;
            int sc = gc - 3; sc = sc < 0 ? -sc : sc; sc = sc >= HW ? 2 * HW - 2 - sc : sc;
            float v = xc[sr * HW + sc];
            if ((unsigned)gr >= 262u || (unsigned)gc >= 262u) v = 0.0f;  // guard slots
            P[c][r] = v;
        }
    }
    __syncthreads();

    // ---- Stage 2: vertical filter, even/odd pair per item -> T[64][.] ----
#pragma unroll
    for (int it = 0; it < 5; ++it) {
        int w = it * BLOCK + tid;      // 0..1279 = 32 pairs x 40 cols
        int k = w / PR;                // pair index 0..31
        int c = w - k * PR;            // col 0..39
        float v[9];
#pragma unroll
        for (int q = 0; q < 9; ++q) v[q] = P[c][k + q];
        float aE = 0.0f, aO = 0.0f;
#pragma unroll
        for (int q = 0; q < 9; ++q) aE = fmaf(wE[q], v[q], aE);
#pragma unroll
        for (int q = 0; q < 8; ++q) aO = fmaf(wO[q], v[q + 1], aO);
        if (ty == 0 && k == 0)    { aE += g7 * P[c][1]; aO += g8 * P[c][1]; }
        if (ty == 448 && k == 31) { aO += g8 * P[c][38]; }
        T[2 * k][c]     = aE;
        T[2 * k + 1][c] = aO;
    }
    __syncthreads();

    // ---- Stage 3: horizontal filter, 4 cols (2 pairs) per item ----
    const float inv_s = 0.25231325f;   // 1/sqrt(5*pi)
    float* oc = out + (size_t)bc * ((size_t)OWID * OWID);
#pragma unroll
    for (int it = 0; it < 4; ++it) {
        int w = it * BLOCK + tid;
        int orow = w >> 4;             // 0..63
        int q4 = w & 15;               // 0..15 -> cols 4q4..4q4+3
        float v[10];
#pragma unroll
        for (int q = 0; q < 10; ++q) v[q] = T[orow][2 * q4 + q];  // ds_read_b64 x5
        float r0 = 0.f, r1 = 0.f, r2 = 0.f, r3 = 0.f;
#pragma unroll
        for (int q = 0; q < 9; ++q) { r0 = fmaf(wE[q], v[q], r0); r2 = fmaf(wE[q], v[q + 1], r2); }
#pragma unroll
        for (int q = 0; q < 8; ++q) { r1 = fmaf(wO[q], v[q + 1], r1); r3 = fmaf(wO[q], v[q + 2], r3); }
        if (tx == 0 && q4 == 0)    { r0 += g7 * T[orow][1]; r1 += g8 * T[orow][1]; }
        if (tx == 448 && q4 == 15) { r3 += g8 * T[orow][38]; }
        float4 o4 = make_float4(r0 * inv_s, r1 * inv_s, r2 * inv_s, r3 * inv_s);
        *reinterpret_cast<float4*>(&oc[(size_t)(ty + orow) * OWID + tx + 4 * q4]) = o4;
    }
}

extern "C" void kernel_launch(void* const* d_in, const int* in_sizes, int n_in,
                              void* d_out, int out_size, void* d_ws, size_t ws_size,
                              hipStream_t stream) {
    const float* x = (const float*)d_in[0];
    const float* f = (const float*)d_in[1];
    float* out = (float*)d_out;
    up2d_kernel<<<dim3(8192), BLOCK, 0, stream>>>(x, f, out);
}

// Round 4
// 34.616 us; speedup vs baseline: 1.5585x; 1.0054x over previous
//
#include <hip/hip_runtime.h>

#define BLOCK 256
#define TILE 64
#define PR 40          // TILE/2 + 8 halo (xp-space)
#define HW 256
#define OWID 512

typedef float f32x2 __attribute__((ext_vector_type(2)));

__global__ __launch_bounds__(BLOCK) void up2d_kernel(
    const float* __restrict__ x,
    const float* __restrict__ f,
    float* __restrict__ out)
{
    __shared__ float P[PR][42];       // P[c][r]; pitch 42 (even) -> b64-aligned rows
    __shared__ float T[TILE][42];     // T[orow][c], pitch 42 keeps 8B align

    const int tid = threadIdx.x;

    // XCD-aware remap: 8192 blocks, 8 XCDs (XCD = id % 8). XCD k gets the
    // contiguous orig-range [1024k, 1024(k+1)): 16 whole images, tiles of each
    // image temporally clustered on ONE XCD -> image fetched from HBM once.
    const int L = blockIdx.x;                       // 0..8191
    const int orig = ((L & 7) << 10) | (L >> 3);    // bijective
    const int bc   = orig >> 6;    // 0..127  (image = batch*channel)
    const int tile = orig & 63;    // 0..63   (8x8 tiles of 64x64)

    const int ty = (tile >> 3) * TILE;
    const int tx = (tile & 7) * TILE;
    const int ry0 = (ty >> 1) - 1;
    const int rx0 = (tx >> 1) - 1;

    // Effective 17-tap filter: g[d], d = |offset|
    float g[9];
    g[0] = 4.0f * f[7];
#pragma unroll
    for (int k = 1; k <= 7; ++k) g[k] = 2.0f * (f[7 + k] + f[6 + k]);
    g[8] = 2.0f * f[14];

    float wE[9], wO[8];
#pragma unroll
    for (int q = 0; q < 9; ++q) { int d = 8 - 2 * q; wE[q] = g[d < 0 ? -d : d]; }
#pragma unroll
    for (int q = 0; q < 8; ++q) { int d = 7 - 2 * q; wO[q] = g[d < 0 ? -d : d]; }
    const float g7 = g[7], g8 = g[8];

    // ---- Stage 1: load 40x40 patch (transposed, zero-guarded) ----
    const float* xc = x + (size_t)bc * (HW * HW);
#pragma unroll
    for (int it = 0; it < 7; ++it) {
        int w = it * BLOCK + tid;
        if (w < PR * PR) {
            int r = w / PR;
            int c = w - r * PR;
            int gr = ry0 + r, gc = rx0 + c;
            int sr = gr - 3; sr = sr < 0 ? -sr : sr; sr = sr >= HW ? 2 * HW - 2 - sr : sr;
            int sc = gc - 3; sc = sc < 0 ? -sc : sc; sc = sc >= HW ? 2 * HW - 2 - sc : sc;
            float v = xc[sr * HW + sc];
            if ((unsigned)gr >= 262u || (unsigned)gc >= 262u) v = 0.0f;  // guard slots
            P[c][r] = v;
        }
    }
    __syncthreads();

    // ---- Stage 2: vertical filter; 2 pairs (4 out rows) per item ----
    // 640 items = 16 k2 x 40 cols; reads = 5x ds_read_b64 (10-float window)
#pragma unroll
    for (int it = 0; it < 3; ++it) {
        int w = it * BLOCK + tid;
        if (w < 640) {
            int k2 = w / PR;            // 0..15 -> pairs 2k2, 2k2+1
            int c  = w - k2 * PR;       // 0..39
            f32x2 b0 = *reinterpret_cast<const f32x2*>(&P[c][2 * k2]);
            f32x2 b1 = *reinterpret_cast<const f32x2*>(&P[c][2 * k2 + 2]);
            f32x2 b2 = *reinterpret_cast<const f32x2*>(&P[c][2 * k2 + 4]);
            f32x2 b3 = *reinterpret_cast<const f32x2*>(&P[c][2 * k2 + 6]);
            f32x2 b4 = *reinterpret_cast<const f32x2*>(&P[c][2 * k2 + 8]);
            float v[10] = {b0.x, b0.y, b1.x, b1.y, b2.x,
                           b2.y, b3.x, b3.y, b4.x, b4.y};
#pragma unroll
            for (int t = 0; t < 2; ++t) {
                float aE = 0.0f, aO = 0.0f;
#pragma unroll
                for (int q = 0; q < 9; ++q) aE = fmaf(wE[q], v[t + q], aE);
#pragma unroll
                for (int q = 0; q < 8; ++q) aO = fmaf(wO[q], v[t + 1 + q], aO);
                int k = 2 * k2 + t;
                if (ty == 0 && k == 0)    { aE += g7 * v[1]; aO += g8 * v[1]; }
                if (ty == 448 && k == 31) { aO += g8 * v[8]; }   // P[c][38]
                T[2 * k][c]     = aE;
                T[2 * k + 1][c] = aO;
            }
        }
    }
    __syncthreads();

    // ---- Stage 3: horizontal filter, 4 cols (2 pairs) per item ----
    const float inv_s = 0.25231325f;   // 1/sqrt(5*pi)
    float* oc = out + (size_t)bc * ((size_t)OWID * OWID);
#pragma unroll
    for (int it = 0; it < 4; ++it) {
        int w = it * BLOCK + tid;
        int orow = w >> 4;             // 0..63
        int q4 = w & 15;               // 0..15 -> cols 4q4..4q4+3
        float v[10];
#pragma unroll
        for (int q = 0; q < 10; ++q) v[q] = T[orow][2 * q4 + q];  // ds_read_b64 x5
        float r0 = 0.f, r1 = 0.f, r2 = 0.f, r3 = 0.f;
#pragma unroll
        for (int q = 0; q < 9; ++q) { r0 = fmaf(wE[q], v[q], r0); r2 = fmaf(wE[q], v[q + 1], r2); }
#pragma unroll
        for (int q = 0; q < 8; ++q) { r1 = fmaf(wO[q], v[q + 1], r1); r3 = fmaf(wO[q], v[q + 2], r3); }
        if (tx == 0 && q4 == 0)    { r0 += g7 * T[orow][1]; r1 += g8 * T[orow][1]; }
        if (tx == 448 && q4 == 15) { r3 += g8 * T[orow][38]; }
        float4 o4 = make_float4(r0 * inv_s, r1 * inv_s, r2 * inv_s, r3 * inv_s);
        *reinterpret_cast<float4*>(&oc[(size_t)(ty + orow) * OWID + tx + 4 * q4]) = o4;
    }
}

extern "C" void kernel_launch(void* const* d_in, const int* in_sizes, int n_in,
                              void* d_out, int out_size, void* d_ws, size_t ws_size,
                              hipStream_t stream) {
    const float* x = (const float*)d_in[0];
    const float* f = (const float*)d_in[1];
    float* out = (float*)d_out;
    up2d_kernel<<<dim3(8192), BLOCK, 0, stream>>>(x, f, out);
}